// Round 11
// baseline (469.566 us; speedup 1.0000x reference)
//
#include <hip/hip_runtime.h>

// 2-layer tanh RNN, T=2048, B=4096, I=3, H=5. f32 storage.
//
// R16: R14/R15 evidence -> each split wave is SOLO on its SIMD and
// latency-bound (~40% issue density; serial dot->tanh->DPP chain), so
// per-wave instruction diets don't move the wall (R15 neutral). Fix:
// 8-wave workgroups (512 thr) force wave->SIMD round-robin to place
// 2 waves/SIMD; the two waves' independent streams fill each other's
// dependency bubbles. 4 producer/consumer pairs per WG (4 chain groups
// x 16 chains), 64 WGs. Packed wall ~ combined issue ~192cy vs solo
// ~258cy. (R12-style waves must NOT be packed: 2x226=452>286 -- packing
// only helps low-issue-density waves.) Wave internals are R14 VERBATIM
// (math, ring layout, schedule) -> absmax must stay 0.00390625.

typedef float v2f  __attribute__((ext_vector_type(2)));
typedef float v2fu __attribute__((ext_vector_type(2), aligned(4)));
typedef float v3fu __attribute__((ext_vector_type(3), aligned(4)));

#define SEQ_T 2048
#define BATCH 4096
#define ISZ 3
#define HSZ 5
#define TBLK 8
#define XSTRIDE (BATCH * ISZ)
#define OSTRIDE (BATCH * HSZ)

template<int K>
__device__ __forceinline__ float qbcast(float v) {
    return __int_as_float(__builtin_amdgcn_mov_dpp(
        __float_as_int(v), K * 0x55, 0xF, 0xF, false));
}
__device__ __forceinline__ v2f vsplat(float s) { return (v2f){s, s}; }
__device__ __forceinline__ v2f vfma(float s, v2f w, v2f a) {
    return __builtin_elementwise_fma(vsplat(s), w, a);  // v_pk_fma_f32
}

__global__ __launch_bounds__(512, 1)
void rnn2_pc8(const float* __restrict__ x, const float* __restrict__ hx,
              const float* __restrict__ w_ih0, const float* __restrict__ w_hh0,
              const float* __restrict__ b_ih0, const float* __restrict__ b_hh0,
              const float* __restrict__ w_ih1, const float* __restrict__ w_hh1,
              const float* __restrict__ b_ih1, const float* __restrict__ b_hh1,
              float* __restrict__ out)
{
    // per-group ring: 48B rows, 8B-aligned b64 ops (R14 layout), x4 groups
    __shared__ float ring[4][2][TBLK][16][12];     // 48 KiB

    const int tid  = threadIdx.x;
    const int wid  = tid >> 6;                      // 0..7
    const int role = wid >> 2;                      // 0 = producer, 1 = consumer
    const int g    = wid & 3;                       // chain group 0..3
    const int lane = tid & 63;
    const int cl   = lane >> 2;                     // chain-local 0..15
    const int ja   = lane & 3;                      // slot A unit
    const int jb   = ja + 1;                        // slot B unit
    const int c    = blockIdx.x * 64 + g * 16 + cl; // chain id 0..4095
    const float S  = 2.8853900817779268f;           // 2*log2(e)

    float (*rg)[TBLK][16][12] = ring[g];

    const v2f bias0p = (v2f){ S * (b_ih0[ja] + b_hh0[ja]), S * (b_ih0[jb] + b_hh0[jb]) };
    const v2f bias1p = (v2f){ S * (b_ih1[ja] + b_hh1[ja]), S * (b_ih1[jb] + b_hh1[jb]) };
#define LW(W, k, n)  (v2f){ S * W[ja * (n) + (k)], S * W[jb * (n) + (k)] }
    const v2f wi0p0 = LW(w_ih0, 0, ISZ), wi0p1 = LW(w_ih0, 1, ISZ), wi0p2 = LW(w_ih0, 2, ISZ);
    const v2f wh0p0 = LW(w_hh0, 0, HSZ), wh0p1 = LW(w_hh0, 1, HSZ), wh0p2 = LW(w_hh0, 2, HSZ),
              wh0p3 = LW(w_hh0, 3, HSZ), wh0p4 = LW(w_hh0, 4, HSZ);
    const v2f wi1p0 = LW(w_ih1, 0, HSZ), wi1p1 = LW(w_ih1, 1, HSZ), wi1p2 = LW(w_ih1, 2, HSZ),
              wi1p3 = LW(w_ih1, 3, HSZ), wi1p4 = LW(w_ih1, 4, HSZ);
    const v2f wh1p0 = LW(w_hh1, 0, HSZ), wh1p1 = LW(w_hh1, 1, HSZ), wh1p2 = LW(w_hh1, 2, HSZ),
              wh1p3 = LW(w_hh1, 3, HSZ), wh1p4 = LW(w_hh1, 4, HSZ);
#undef LW

    float h0b0 = hx[(size_t)c * HSZ + 0], h0b1 = hx[(size_t)c * HSZ + 1],
          h0b2 = hx[(size_t)c * HSZ + 2], h0b3 = hx[(size_t)c * HSZ + 3],
          h0b4 = hx[(size_t)c * HSZ + 4];
    const size_t hb1 = (size_t)BATCH * HSZ + (size_t)c * HSZ;
    float h1b0 = hx[hb1 + 0], h1b1 = hx[hb1 + 1], h1b2 = hx[hb1 + 2],
          h1b3 = hx[hb1 + 3], h1b4 = hx[hb1 + 4];

    // ---- producer x block buffers ----
    unsigned xoff = (unsigned)c * ISZ;
    v3fu xA0, xA1, xA2, xA3, xA4, xA5, xA6, xA7;
    v3fu xB0, xB1, xB2, xB3, xB4, xB5, xB6, xB7;
#define LOADX(P)                                                           \
    {                                                                      \
        P##0 = *(const v3fu*)(x + xoff + 0*XSTRIDE);                       \
        P##1 = *(const v3fu*)(x + xoff + 1*XSTRIDE);                       \
        P##2 = *(const v3fu*)(x + xoff + 2*XSTRIDE);                       \
        P##3 = *(const v3fu*)(x + xoff + 3*XSTRIDE);                       \
        P##4 = *(const v3fu*)(x + xoff + 4*XSTRIDE);                       \
        P##5 = *(const v3fu*)(x + xoff + 5*XSTRIDE);                       \
        P##6 = *(const v3fu*)(x + xoff + 6*XSTRIDE);                       \
        P##7 = *(const v3fu*)(x + xoff + 7*XSTRIDE);                       \
        xoff += 8u * XSTRIDE;                                              \
    }

    unsigned ooff = (unsigned)c * HSZ + (unsigned)ja;   // consumer out ptr
    float g0, g1, g2, g3, g4;                           // consumer h0 stage

// producer step (R14 verbatim)
#define STEP0(XV, WR, TT)                                                  \
    {                                                                      \
        v2f a = bias0p, cc = (v2f){0.0f, 0.0f};                            \
        a  = vfma(XV.x,  wi0p0, a);                                        \
        cc = vfma(XV.y,  wi0p1, cc);                                       \
        a  = vfma(XV.z,  wi0p2, a);                                        \
        cc = vfma(h0b0, wh0p0, cc);                                        \
        a  = vfma(h0b1, wh0p1, a);                                         \
        cc = vfma(h0b2, wh0p2, cc);                                        \
        a  = vfma(h0b3, wh0p3, a);                                         \
        cc = vfma(h0b4, wh0p4, cc);                                        \
        a = a + cc;                                                        \
        v2f e0;                                                            \
        e0.x = __builtin_amdgcn_exp2f(a.x);                                \
        e0.y = __builtin_amdgcn_exp2f(a.y);                                \
        const v2f p0 = e0 + vsplat(1.0f);                                  \
        v2f r0;                                                            \
        r0.x = __builtin_amdgcn_rcpf(p0.x);                                \
        r0.y = __builtin_amdgcn_rcpf(p0.y);                                \
        const v2f n0 = __builtin_elementwise_fma(vsplat(-2.0f), r0, vsplat(1.0f)); \
        h0b0 = qbcast<0>(n0.x);                                            \
        h0b1 = qbcast<1>(n0.x);                                            \
        h0b2 = qbcast<2>(n0.x);                                            \
        h0b3 = qbcast<3>(n0.x);                                            \
        h0b4 = qbcast<3>(n0.y);                                            \
        *(v2f*)&WR[TT][cl][ja * 2] = n0;                                   \
    }

#define PBLOCK(P, RB)                                                      \
    {                                                                      \
        float (*wr)[16][12] = rg[RB];                                      \
        STEP0(P##0, wr, 0)                                                 \
        STEP0(P##1, wr, 1)                                                 \
        STEP0(P##2, wr, 2)                                                 \
        STEP0(P##3, wr, 3)                                                 \
        STEP0(P##4, wr, 4)                                                 \
        STEP0(P##5, wr, 5)                                                 \
        STEP0(P##6, wr, 6)                                                 \
        STEP0(P##7, wr, 7)                                                 \
    }

// consumer step (R14 verbatim): 1-step LDS prefetch, inline store
#define STEP1(RD, TT, DOPRE)                                               \
    {                                                                      \
        const float u0 = g0, u1 = g1, u2 = g2, u3 = g3, u4 = g4;           \
        if (DOPRE) {                                                       \
            g0 = RD[(TT) + 1][cl][0];                                      \
            g1 = RD[(TT) + 1][cl][2];                                      \
            g2 = RD[(TT) + 1][cl][4];                                      \
            g3 = RD[(TT) + 1][cl][6];                                      \
            g4 = RD[(TT) + 1][cl][7];                                      \
        }                                                                  \
        v2f d = bias1p, ee = (v2f){0.0f, 0.0f};                            \
        d  = vfma(u0,   wi1p0, d);                                         \
        ee = vfma(u1,   wi1p1, ee);                                        \
        d  = vfma(u2,   wi1p2, d);                                         \
        ee = vfma(u3,   wi1p3, ee);                                        \
        d  = vfma(u4,   wi1p4, d);                                         \
        ee = vfma(h1b0, wh1p0, ee);                                        \
        d  = vfma(h1b1, wh1p1, d);                                         \
        ee = vfma(h1b2, wh1p2, ee);                                        \
        d  = vfma(h1b3, wh1p3, d);                                         \
        ee = vfma(h1b4, wh1p4, ee);                                        \
        d = d + ee;                                                        \
        v2f e1;                                                            \
        e1.x = __builtin_amdgcn_exp2f(d.x);                                \
        e1.y = __builtin_amdgcn_exp2f(d.y);                                \
        const v2f p1 = e1 + vsplat(1.0f);                                  \
        v2f r1;                                                            \
        r1.x = __builtin_amdgcn_rcpf(p1.x);                                \
        r1.y = __builtin_amdgcn_rcpf(p1.y);                                \
        const v2f n1 = __builtin_elementwise_fma(vsplat(-2.0f), r1, vsplat(1.0f)); \
        *(v2fu*)(out + ooff) = n1;                                         \
        ooff += OSTRIDE;                                                   \
        h1b0 = qbcast<0>(n1.x);                                            \
        h1b1 = qbcast<1>(n1.x);                                            \
        h1b2 = qbcast<2>(n1.x);                                            \
        h1b3 = qbcast<3>(n1.x);                                            \
        h1b4 = qbcast<3>(n1.y);                                            \
    }

#define CBLOCK(RB)                                                         \
    {                                                                      \
        const float (*rd)[16][12] = rg[RB];                                \
        g0 = rd[0][cl][0];                                                 \
        g1 = rd[0][cl][2];                                                 \
        g2 = rd[0][cl][4];                                                 \
        g3 = rd[0][cl][6];                                                 \
        g4 = rd[0][cl][7];                                                 \
        STEP1(rd, 0, 1)                                                    \
        STEP1(rd, 1, 1)                                                    \
        STEP1(rd, 2, 1)                                                    \
        STEP1(rd, 3, 1)                                                    \
        STEP1(rd, 4, 1)                                                    \
        STEP1(rd, 5, 1)                                                    \
        STEP1(rd, 6, 1)                                                    \
        STEP1(rd, 7, 0)                                                    \
    }

    // ---- prologue: producers load block 0 ----
    if (role == 0) { LOADX(xA) }

    __syncthreads();
    if (role == 0) { LOADX(xB) PBLOCK(xA, 0) }

    // steady pairs: 127
    for (int sp = 0; sp < 127; ++sp) {
        __syncthreads();
        if (role == 0) { LOADX(xA) PBLOCK(xB, 1) } else { CBLOCK(0) }
        __syncthreads();
        if (role == 0) { LOADX(xB) PBLOCK(xA, 0) } else { CBLOCK(1) }
    }

    // producer's last block (255); consumer block 254
    __syncthreads();
    if (role == 0) { PBLOCK(xB, 1) } else { CBLOCK(0) }

    // consumer drains block 255
    __syncthreads();
    if (role != 0) { CBLOCK(1) }

#undef STEP0
#undef STEP1
#undef PBLOCK
#undef CBLOCK
#undef LOADX

    // h_n = [h0_final, h1_final] after out[T,B,H]; quad-dup stores benign
    float* hn = out + (size_t)SEQ_T * BATCH * HSZ;
    if (role == 0) {
        hn[(size_t)c * HSZ + 0] = h0b0;
        hn[(size_t)c * HSZ + 1] = h0b1;
        hn[(size_t)c * HSZ + 2] = h0b2;
        hn[(size_t)c * HSZ + 3] = h0b3;
        hn[(size_t)c * HSZ + 4] = h0b4;
    } else {
        hn[hb1 + 0] = h1b0;
        hn[hb1 + 1] = h1b1;
        hn[hb1 + 2] = h1b2;
        hn[hb1 + 3] = h1b3;
        hn[hb1 + 4] = h1b4;
    }
}

extern "C" void kernel_launch(void* const* d_in, const int* in_sizes, int n_in,
                              void* d_out, int out_size, void* d_ws, size_t ws_size,
                              hipStream_t stream) {
    // 64 blocks x 512 threads: 8 waves/WG -> 2 waves per SIMD (round-robin),
    // 4 producer/consumer pairs per WG, 64 chains/WG.
    rnn2_pc8<<<BATCH / 64, 512, 0, stream>>>(
        (const float*)d_in[0], (const float*)d_in[1],
        (const float*)d_in[2], (const float*)d_in[3],
        (const float*)d_in[4], (const float*)d_in[5],
        (const float*)d_in[6], (const float*)d_in[7],
        (const float*)d_in[8], (const float*)d_in[9],
        (float*)d_out);
}